// Round 5
// baseline (290.384 us; speedup 1.0000x reference)
//
#include <hip/hip_runtime.h>
#include <hip/hip_bf16.h>

// ---------------------------------------------------------------------------
// SelfAttentionHybrid: single-head attention, B=4 S=2048 E=1024, fp32 in/out.
// R11: distance-2 staging + stall-free counted vmcnt. R10 measured 4673
// cy/K-tile (m201-class structure = 3300). R10's one non-counted wait was
// vmcnt(0) at ph2-close, draining staging issued only ~1-2 phases earlier
// (marginal vs HBM latency -> real stall, all waves together). R11 stages
// tile kt+2 during tile kt (B at ph2, A at ph3); each vmcnt(8) retires loads
// issued 6-7 phases (~2500 cy) earlier -> never blocks (m218's counted-vs-
// drain0 isolated at +38-73% in this structure).
//
// Per-tile schedule (cb = kt&1; bc = B0(kt) regs read at prev ph3):
//  ph0: issue 8 A0 reads;         LGKM{6,4,2,0} x G_AQ(bc)      [no barrier]
//  ph1: issue 4 B1 reads;         LGKM{2,0} x G_BQ;             BARRIER
//       (all B(cb) ds_reads CU-wide complete -> B region writable)
//  ph2: issue 8 A1 reads; issue stageB(kt+2); LGKM{6,4,2,0} x G_AQ(bq);
//       VM(8) [retire B(kt+1), issued kt-1 ph2];                BARRIER
//       (all A(cb) reads complete; B(kt+1) visible CU-wide)
//  ph3: issue 4 B0(kt+1) reads (buf cb^1); issue stageA(kt+2);
//       G_AQ(bc) reg-only; VM(8) [retire A(kt+1)];              BARRIER
// Steady-state vmem bookkeeping (per wave): entering ph2 in flight =
// {B(kt+1) 4, A(kt+1) 4}; +B(kt+2) 4 = 12 -> VM(8) retires B(kt+1);
// ph3 +A(kt+2) = 12 -> VM(8) retires A(kt+1). Tail: kt=NT-2 -> VM(4)/VM(0)
// (both stall-free, loads 6+ phases old); kt=NT-1 -> no staging/vmcnt.
// ---------------------------------------------------------------------------

typedef __bf16 bf16_t;
typedef __bf16 bf16x8 __attribute__((ext_vector_type(8)));
typedef __bf16 bf16x4 __attribute__((ext_vector_type(4)));
typedef float  f32x16 __attribute__((ext_vector_type(16)));
typedef float  f32x4  __attribute__((ext_vector_type(4)));

__device__ __forceinline__ void async_copy16(const void* g, void* l) {
  __builtin_amdgcn_global_load_lds(
      (const __attribute__((address_space(1))) void*)g,
      (__attribute__((address_space(3))) void*)l, 16, 0, 0);
}

// raw workgroup barrier: NO vmcnt/lgkmcnt drain (unlike __syncthreads).
__device__ __forceinline__ void wg_barrier() {
  asm volatile("" ::: "memory");
  __builtin_amdgcn_s_barrier();
  asm volatile("" ::: "memory");
}

// counted LDS wait + rule-18 scheduler pin (MFMAs must not hoist above it)
#define LGKM(n)                                                  \
  do {                                                           \
    asm volatile("s_waitcnt lgkmcnt(" #n ")" ::: "memory");      \
    __builtin_amdgcn_sched_barrier(0);                           \
  } while (0)

// counted VMEM wait (retires oldest outstanding global_load_lds)
#define VM(n) asm volatile("s_waitcnt vmcnt(" #n ")" ::: "memory")

// 32-bit LDS byte address (for asm ds_read; invisible to alias analysis)
__device__ __forceinline__ unsigned lds_addr(const void* p) {
  return (unsigned)(unsigned long long)(__attribute__((address_space(3))) const void*)p;
}

// inline-asm LDS read: compiler cannot see this as an LDS access, so it does
// NOT insert vmcnt(0) ordering vs in-flight global_load_lds prefetches.
// Ordering enforced manually via LGKM() + counted VM() + barriers.
__device__ __forceinline__ bf16x8 ds_read128(const bf16_t* p) {
  bf16x8 r;
  asm volatile("ds_read_b128 %0, %1" : "=v"(r) : "v"(lds_addr(p)));
  return r;
}

__device__ __forceinline__ f32x4 mfma16(bf16x8 a, bf16x8 b, f32x4 c) {
  return __builtin_amdgcn_mfma_f32_16x16x32_bf16(a, b, c, 0, 0, 0);
}

__device__ __forceinline__ void store_out(float* p, float v)  { *p = v; }
__device__ __forceinline__ void store_out(bf16_t* p, float v) { *p = (bf16_t)v; }

#define BM 128
#define BN 128
#define BKT 64

// 4 MFMA: a[i] x bb -> acc[ro+i][co..co+1], both k-slices
#define G_AQ(i, ro, bb, co)                                                   \
  acc[(ro) + (i)][(co) + 0] = mfma16(a[i][0], bb[0][0], acc[(ro) + (i)][(co) + 0]); \
  acc[(ro) + (i)][(co) + 1] = mfma16(a[i][0], bb[1][0], acc[(ro) + (i)][(co) + 1]); \
  acc[(ro) + (i)][(co) + 0] = mfma16(a[i][1], bb[0][1], acc[(ro) + (i)][(co) + 0]); \
  acc[(ro) + (i)][(co) + 1] = mfma16(a[i][1], bb[1][1], acc[(ro) + (i)][(co) + 1]);

// 8 MFMA: all a[i] x bb[j] -> acc[0..3][co+j], both k-slices
#define G_BQ(j, bb, co)                                              \
  acc[0][(co) + (j)] = mfma16(a[0][0], bb[j][0], acc[0][(co) + (j)]); \
  acc[1][(co) + (j)] = mfma16(a[1][0], bb[j][0], acc[1][(co) + (j)]); \
  acc[2][(co) + (j)] = mfma16(a[2][0], bb[j][0], acc[2][(co) + (j)]); \
  acc[3][(co) + (j)] = mfma16(a[3][0], bb[j][0], acc[3][(co) + (j)]); \
  acc[0][(co) + (j)] = mfma16(a[0][1], bb[j][1], acc[0][(co) + (j)]); \
  acc[1][(co) + (j)] = mfma16(a[1][1], bb[j][1], acc[1][(co) + (j)]); \
  acc[2][(co) + (j)] = mfma16(a[2][1], bb[j][1], acc[2][(co) + (j)]); \
  acc[3][(co) + (j)] = mfma16(a[3][1], bb[j][1], acc[3][(co) + (j)]);

// ---------------------------------------------------------------------------
// gemm256_bt: C[M,N] = A[M,K](lda) x B[N,K](ldb)^T * scale + bias.
// 512 thr = 8 waves (2Mx4N); wave tile 128x64 = 8x4 frags of 16x16x32 MFMA.
// LDS [2 buf][256 rows][64 bf16] per matrix; slot (r,cc) holds global chunk
// cc^(r&7); reads use slot kc^(r&7) (involution).
// Requires M%256==0, N%256==0, K%128==0 (NT even, NT>=4), gridDim.y%8==0.
// ---------------------------------------------------------------------------
template <typename OutT, int NBIAS>
__global__ __launch_bounds__(512, 2) void gemm256_bt(
    const bf16_t* __restrict__ A, const bf16_t* __restrict__ B,
    OutT* __restrict__ C,
    const float* __restrict__ b0, const float* __restrict__ b1,
    const float* __restrict__ b2,
    int M, int N, int K, int lda, int ldb, int ldc, float scale,
    long long strideA, long long strideB, long long strideC) {
  const int z = blockIdx.z;
  A += (long long)z * strideA;
  B += (long long)z * strideB;
  C += (long long)z * strideC;

  // L2 supertile remap: 8 y-tiles per supertile, y-fastest inside.
  int bx = blockIdx.x, by = blockIdx.y;
  {
    const int GX  = gridDim.x;
    const int id  = by * GX + bx;
    const int per = GX * 8;
    const int grp = id / per;
    const int rem = id - grp * per;
    by = grp * 8 + (rem & 7);
    bx = rem >> 3;
  }

  __shared__ __align__(16) bf16_t As[2 * 256 * 64];  // 64 KB
  __shared__ __align__(16) bf16_t Bs[2 * 256 * 64];  // 64 KB

  const int t    = threadIdx.x;
  const int lane = t & 63;
  const int w    = t >> 6;
  const int wm   = w & 1;    // M-half of output tile
  const int wn   = w >> 1;   // N-quarter of output tile
  const int g    = lane >> 4;
  const int l7   = lane & 7;
  const int r15  = lane & 15;
  const int tileM = by * 256;
  const int tileN = bx * 256;

  // staging constants: thread covers chunks t and t+512 of each half-tile
  const int row0 = t >> 3;                    // 0..63
  const int gcc  = (t & 7) ^ (row0 & 7);      // swizzled source chunk
  const int dstb = (t & ~63) * 8;             // wave-uniform LDS base (elems)

  // read constants
  const int sw0 = ((0 + g) ^ l7) * 8;         // k-slice 0 chunk offset (elems)
  const int sw1 = ((4 + g) ^ l7) * 8;         // k-slice 1
  const int aRow = (wm * 128 + r15) * 64;
  const int bRow = (wn * 64 + r15) * 64;

  const int NT = K >> 6;

  f32x4 acc[8][4] = {};

  auto stageA = [&](int kt, int h) {
    const int cb = (kt & 1) * 16384;
    const bf16_t* src =
        A + (long long)(tileM + h * 128 + row0) * lda + kt * 64 + gcc * 8;
    bf16_t* dst = &As[cb + h * 8192 + dstb];
    async_copy16(src, dst);
    async_copy16(src + (long long)64 * lda, dst + 4096);
  };
  auto stageB = [&](int kt, int h) {
    const int cb = (kt & 1) * 16384;
    const bf16_t* src =
        B + (long long)(tileN + h * 128 + row0) * ldb + kt * 64 + gcc * 8;
    bf16_t* dst = &Bs[cb + h * 8192 + dstb];
    async_copy16(src, dst);
    async_copy16(src + (long long)64 * ldb, dst + 4096);
  };

  // prologue: stage tiles 0 and 1 (16 loads, tile 0 oldest); retire tile 0,
  // keep tile 1's 8 in flight (steady-state invariant entering ph2 of kt=0).
  stageA(0, 0); stageA(0, 1); stageB(0, 0); stageB(0, 1);
  stageB(1, 0); stageB(1, 1); stageA(1, 0); stageA(1, 1);
  VM(8);
  wg_barrier();

  bf16x8 a[4][2], P[2][2], Q[2][2];
  // pre-read B0(0) (4 reads stay outstanding into tile 0 ph0)
#pragma unroll
  for (int j = 0; j < 2; ++j) {
    P[j][0] = ds_read128(&Bs[bRow + j * 1024 + sw0]);
    P[j][1] = ds_read128(&Bs[bRow + j * 1024 + sw1]);
  }

  // bc = B0(kt) (read at prev ph3); bq = scratch: gets B1(kt) then B0(kt+1)
  auto tile_step = [&](int kt, bf16x8 (&bc)[2][2], bf16x8 (&bq)[2][2]) {
    const int cb = (kt & 1) * 16384;
    const int kn = kt + 1;
    const int k2 = kt + 2;
    const bf16_t* Ab = &As[cb + aRow];
    const bf16_t* Bb = &Bs[cb + bRow];

    // ---- ph0: issue A0 reads (outstanding lgkm 4+8=12); MFMA M0N0(bc).
#pragma unroll
    for (int i = 0; i < 4; ++i) {
      a[i][0] = ds_read128(Ab + i * 1024 + sw0);
      a[i][1] = ds_read128(Ab + i * 1024 + sw1);
    }
    __builtin_amdgcn_s_setprio(1);
    LGKM(6);  // retires B0(kt) x4 + a[0] pair
    G_AQ(0, 0, bc, 0)
    LGKM(4);
    G_AQ(1, 0, bc, 0)
    LGKM(2);
    G_AQ(2, 0, bc, 0)
    LGKM(0);
    G_AQ(3, 0, bc, 0)
    __builtin_amdgcn_s_setprio(0);

    // ---- ph1: issue B1 reads (4); MFMA M0N1(bq); barrier.
#pragma unroll
    for (int j = 0; j < 2; ++j) {
      bq[j][0] = ds_read128(Bb + 2048 + j * 1024 + sw0);
      bq[j][1] = ds_read128(Bb + 2048 + j * 1024 + sw1);
    }
    __builtin_amdgcn_s_setprio(1);
    LGKM(2);  // bq[0] ready
    G_BQ(0, bq, 2)
    LGKM(0);  // bq[1] ready
    G_BQ(1, bq, 2)
    __builtin_amdgcn_s_setprio(0);
    wg_barrier();  // all B(cb) ds_reads complete CU-wide -> B region writable

    // ---- ph2: issue A1 reads (8); issue stageB(kt+2) into cb (safe);
    //           MFMA M1N1(bq); VM(8) retires B(kt+1) [6 phases old]; barrier.
#pragma unroll
    for (int i = 0; i < 4; ++i) {
      a[i][0] = ds_read128(Ab + 4096 + i * 1024 + sw0);
      a[i][1] = ds_read128(Ab + 4096 + i * 1024 + sw1);
    }
    if (k2 < NT) { stageB(k2, 0); stageB(k2, 1); }
    __builtin_amdgcn_s_setprio(1);
    LGKM(6);
    G_AQ(0, 4, bq, 2)
    LGKM(4);
    G_AQ(1, 4, bq, 2)
    LGKM(2);
    G_AQ(2, 4, bq, 2)
    LGKM(0);
    G_AQ(3, 4, bq, 2)
    __builtin_amdgcn_s_setprio(0);
    if (k2 < NT)      { VM(8); }   // retire B(kt+1) staging
    else if (kn < NT) { VM(4); }   // tail kt==NT-2: retire B(NT-1)
    wg_barrier();  // B(kt+1) visible CU-wide; all A(cb) reads complete

    // ---- ph3: read B0(kt+1) from cb^1 -> bq (drains under next ph0 LGKM);
    //           issue stageA(kt+2) into cb (safe); MFMA M1N0(bc) reg-only;
    //           VM(8) retires A(kt+1); barrier.
    if (kn < NT) {
      const bf16_t* Bn = &Bs[(kn & 1) * 16384 + bRow];
#pragma unroll
      for (int j = 0; j < 2; ++j) {
        bq[j][0] = ds_read128(Bn + j * 1024 + sw0);
        bq[j][1] = ds_read128(Bn + j * 1024 + sw1);
      }
    }
    if (k2 < NT) { stageA(k2, 0); stageA(k2, 1); }
    __builtin_amdgcn_s_setprio(1);
    G_AQ(0, 4, bc, 0)
    G_AQ(1, 4, bc, 0)
    G_AQ(2, 4, bc, 0)
    G_AQ(3, 4, bc, 0)
    __builtin_amdgcn_s_setprio(0);
    if (k2 < NT)      { VM(8); }   // retire A(kt+1) staging
    else if (kn < NT) { VM(0); }   // tail kt==NT-2: retire A(NT-1), stall-free
    wg_barrier();  // A(kt+1) visible CU-wide
  };

  for (int kt = 0; kt < NT; kt += 2) {
    tile_step(kt,     P, Q);   // bc = P holds B0(kt);   Q gets B1, B0(kt+1)
    tile_step(kt + 1, Q, P);   // bc = Q holds B0(kt+1); P gets B1, B0(kt+2)
  }

  // epilogue: 16x16 C map: col = lane&15, row = (lane>>4)*4 + r.
  // j innermost: 4 consecutive 32B segments per row -> 128B write-combining.
  float bvv[4];
#pragma unroll
  for (int j = 0; j < 4; ++j) {
    const int col = tileN + wn * 64 + j * 16 + r15;
    float bv = 0.f;
    if (NBIAS == 1) bv = b0[col];
    if (NBIAS == 3) {
      const float* bp = col < 1024 ? b0 : (col < 2048 ? b1 : b2);
      bv = bp[col & 1023];
    }
    bvv[j] = bv;
  }
#pragma unroll
  for (int i = 0; i < 8; ++i) {
#pragma unroll
    for (int r = 0; r < 4; ++r) {
      const long long row = tileM + wm * 128 + i * 16 + g * 4 + r;
      OutT* Crow = C + row * ldc + tileN + wn * 64 + r15;
#pragma unroll
      for (int j = 0; j < 4; ++j)
        store_out(Crow + j * 16, acc[i][j][r] * scale + bvv[j]);
    }
  }
}

// ---------------------------------------------------------------------------
// 128^2 kernel (R6) — kept for PV and output GEMMs (their 256^2 grids would
// be 128 blocks = half the CUs).
// ---------------------------------------------------------------------------
template <typename OutT, int NBIAS>
__global__ __launch_bounds__(256) void gemm_bt(
    const bf16_t* __restrict__ A, const bf16_t* __restrict__ B,
    OutT* __restrict__ C,
    const float* __restrict__ b0, const float* __restrict__ b1,
    const float* __restrict__ b2,
    int M, int N, int K, int lda, int ldb, int ldc, float scale,
    long long strideA, long long strideB, long long strideC) {
  const int z = blockIdx.z;
  A += (long long)z * strideA;
  B += (long long)z * strideB;
  C += (long long)z * strideC;

  int bx = blockIdx.x, by = blockIdx.y;
  {
    const int GX  = gridDim.x;
    const int id  = by * GX + bx;
    const int per = GX * 8;
    const int grp = id / per;
    const int rem = id - grp * per;
    by = grp * 8 + (rem & 7);
    bx = rem >> 3;
  }

  __shared__ __align__(16) bf16_t As[BM * BKT];  // 16 KB
  __shared__ __align__(16) bf16_t Bs[BN * BKT];  // 16 KB

  const int t    = threadIdx.x;
  const int lane = t & 63;
  const int w    = t >> 6;
  const int wm   = w & 1;
  const int wn   = w >> 1;
  const int tileM = by * BM;
  const int tileN = bx * BN;

  f32x16 acc[2][2] = {};

  for (int k0 = 0; k0 < K; k0 += BKT) {
#pragma unroll
    for (int i = 0; i < 4; ++i) {
      const int c   = t + 256 * i;
      const int row = c >> 3;
      const int cc  = c & 7;
      const int gcc = cc ^ (row & 7);
      const int ldsbase = ((t & ~63) + 256 * i) * 8;
      async_copy16(A + (long long)(tileM + row) * lda + k0 + gcc * 8, &As[ldsbase]);
      async_copy16(B + (long long)(tileN + row) * ldb + k0 + gcc * 8, &Bs[ldsbase]);
    }
    __syncthreads();

#pragma unroll
    for (int s = 0; s < 4; ++s) {
      const int kc = s + 4 * (lane >> 5);
      bf16x8 af[2], bfr[2];
#pragma unroll
      for (int ti = 0; ti < 2; ++ti) {
        const int row = wm * 64 + ti * 32 + (lane & 31);
        af[ti] = *(const bf16x8*)&As[row * BKT + ((kc ^ (row & 7)) * 8)];
      }
#pragma unroll
      for (int tj = 0; tj < 2; ++tj) {
        const int row = wn * 64 + tj * 32 + (lane & 31);
        bfr[tj] = *(const bf16x8*)&Bs[row * BKT + ((kc ^ (row & 7)) * 8)];
      }
#pragma unroll
      for (int ti = 0; ti < 2; ++ti)
#pragma unroll
        for (int tj = 0; tj < 2; ++tj)
          acc[ti][tj] = __builtin_amdgcn_mfma_f32_32x32x16_bf16(
              af[ti], bfr[tj], acc[ti][tj], 0, 0, 0);
    }
    __syncthreads();
  }

#pragma unroll
  for (int tj = 0; tj < 2; ++tj) {
    const int col = tileN + wn * 64 + tj * 32 + (lane & 31);
    float bv = 0.f;
    if (NBIAS == 1) bv = b0[col];
    if (NBIAS == 3) {
      const float* bp = col < 1024 ? b0 : (col < 2048 ? b1 : b2);
      bv = bp[col & 1023];
    }
#pragma unroll
    for (int ti = 0; ti < 2; ++ti) {
      const int rowb = tileM + wm * 64 + ti * 32 + 4 * (lane >> 5);
#pragma unroll
      for (int r = 0; r < 16; ++r) {
        const int row = rowb + (r & 3) + 8 * (r >> 2);
        store_out(&C[(long long)row * ldc + col], acc[ti][tj][r] * scale + bv);
      }
    }
  }
}

// ---------------------------------------------------------------------------
// fused cast: all 4 weights + x in one dispatch (flat grid, region decode).
// ---------------------------------------------------------------------------
__global__ __launch_bounds__(256) void cast_all(
    const float4* __restrict__ w0, const float4* __restrict__ w1,
    const float4* __restrict__ w2, const float4* __restrict__ w3,
    const float4* __restrict__ x,
    bf16x4* __restrict__ wdst, bf16x4* __restrict__ xdst) {
  const int N4W = 1 << 18;  // 1024*1024/4
  const int id = blockIdx.x * 256 + threadIdx.x;
  const float4* src;
  bf16x4* dst;
  if (id < 4 * N4W) {
    const int z = id >> 18;
    src = (z == 0 ? w0 : z == 1 ? w1 : z == 2 ? w2 : w3) + (id & (N4W - 1));
    dst = wdst + id;
  } else {
    const int i = id - 4 * N4W;
    src = x + i;
    dst = xdst + i;
  }
  const float4 v = *src;
  bf16x4 o;
  o[0] = (bf16_t)v.x; o[1] = (bf16_t)v.y; o[2] = (bf16_t)v.z; o[3] = (bf16_t)v.w;
  *dst = o;
}

// ---------------------------------------------------------------------------
// bf16 transpose [R,C](ldin) -> [C,R], batched via blockIdx.z
// ---------------------------------------------------------------------------
__global__ __launch_bounds__(256) void transpose_bf16(
    const bf16_t* __restrict__ in, bf16_t* __restrict__ out, int R, int C,
    int ldin, long long sIn, long long sOut) {
  in  += (long long)blockIdx.z * sIn;
  out += (long long)blockIdx.z * sOut;
  __shared__ bf16_t tile[32][33];
  const int tx = threadIdx.x, ty = threadIdx.y;
  const int x = blockIdx.x * 32 + tx;
  const int y0 = blockIdx.y * 32;
#pragma unroll
  for (int j = 0; j < 32; j += 8)
    tile[ty + j][tx] = in[(long long)(y0 + ty + j) * ldin + x];
  __syncthreads();
  const int x2 = y0 + tx;
  const int y2 = blockIdx.x * 32;
#pragma unroll
  for (int j = 0; j < 32; j += 8)
    out[(long long)(y2 + ty + j) * R + x2] = tile[tx][ty + j];
}

// ---------------------------------------------------------------------------
// row softmax: 2048-wide rows, 256 threads x 8 elems
// ---------------------------------------------------------------------------
__global__ __launch_bounds__(256) void softmax_rows(
    const bf16_t* __restrict__ S, bf16_t* __restrict__ P, int cols) {
  const long long row = blockIdx.x;
  const bf16x8* inp = (const bf16x8*)(S + row * cols);
  bf16x8* outp      = (bf16x8*)(P + row * cols);
  const int t = threadIdx.x;
  const int w = t >> 6, lane = t & 63;

  const bf16x8 v = inp[t];
  float f[8];
#pragma unroll
  for (int j = 0; j < 8; ++j) f[j] = (float)v[j];

  float m = f[0];
#pragma unroll
  for (int j = 1; j < 8; ++j) m = fmaxf(m, f[j]);
#pragma unroll
  for (int off = 32; off > 0; off >>= 1) m = fmaxf(m, __shfl_xor(m, off));

  __shared__ float red[8];
  if (lane == 0) red[w] = m;
  __syncthreads();
  m = fmaxf(fmaxf(red[0], red[1]), fmaxf(red[2], red[3]));

  float e[8], sum = 0.f;
#pragma unroll
  for (int j = 0; j < 8; ++j) { e[j] = __expf(f[j] - m); sum += e[j]; }
#pragma unroll
  for (int off = 32; off > 0; off >>= 1) sum += __shfl_xor(sum, off);
  if (lane == 0) red[4 + w] = sum;
  __syncthreads();
  sum = red[4] + red[5] + red[6] + red[7];

  const float inv = 1.f / sum;
  bf16x8 o;
#pragma unroll
  for (int j = 0; j < 8; ++j) o[j] = (bf16_t)(e[j] * inv);
  outp[t] = o;
}

// ---------------------------------------------------------------------------
extern "C" void kernel_launch(void* const* d_in, const int* in_sizes, int n_in,
                              void* d_out, int out_size, void* d_ws, size_t ws_size,
                              hipStream_t stream) {
  const int E = 1024, S = 2048, B = 4;
  const int BS = B * S;  // 8192

  const float* x  = (const float*)d_in[0];
  const float* Wq = (const float*)d_in[1];
  const float* bq = (const float*)d_in[2];
  const float* Wk = (const float*)d_in[3];
  const float* bk = (const float*)d_in[4];
  const float* Wv = (const float*)d_in[5];
  const float* bv = (const float*)d_in[6];
  const float* Wo = (const float*)d_in[7];
  const float* bo = (const float*)d_in[8];
  float* out = (float*)d_out;

  char* w = (char*)d_ws;
  const size_t MB = 1ull << 20;
  bf16_t* Wqkvb = (bf16_t*)(w + 0 * MB);          // 6 MB  [3072,1024]
  bf16_t* Wob   = Wqkvb + 3 * E * E;              // 2 MB
  bf16_t* xb    = (bf16_t*)(w + 8 * MB);          // 16 MB [8192,1024]
  bf16_t* QKVb  = (bf16_t*)(w + 24 * MB);         // 48 MB [8192,3072]
  bf16_t* VTb   = (bf16_t*)(w + 72 * MB);         // 16 MB [B][1024,2048]
  bf16_t* Sb    = (bf16_t*)(w + 88 * MB);         // 32 MB scores
  bf16_t* Pb    = (bf16_t*)(w + 8 * MB);          // 32 MB (xb + QKV[0:16MB] dead)
  bf16_t* Ob    = (bf16_t*)(w + 40 * MB);         // 16 MB (QKV[16:32MB] dead)

  // ---- all casts in one dispatch
  {
    const int totalBlocks = ((4 << 18) + (1 << 21)) / 256;  // 12288
    cast_all<<<totalBlocks, 256, 0, stream>>>(
        (const float4*)Wq, (const float4*)Wk, (const float4*)Wv,
        (const float4*)Wo, (const float4*)x, (bf16x4*)Wqkvb, (bf16x4*)xb);
  }

  // ---- fused QKV projection: [8192,3072] = xb . Wqkv^T + (bq|bk|bv)
  gemm256_bt<bf16_t, 3><<<dim3(3 * E / 256, BS / 256, 1), 512, 0, stream>>>(
      xb, Wqkvb, QKVb, bq, bk, bv,
      BS, 3 * E, E, E, E, 3 * E, 1.f, 0, 0, 0);

  // ---- V^T per batch: [2048,1024](ld 3072) -> [1024,2048]
  transpose_bf16<<<dim3(E / 32, S / 32, B), dim3(32, 8), 0, stream>>>(
      QKVb + 2 * E, VTb, S, E, 3 * E, (long long)S * 3 * E, (long long)E * S);

  // ---- scores = Q . K^T * E^-0.5 per batch
  gemm256_bt<bf16_t, 0><<<dim3(S / 256, S / 256, B), 512, 0, stream>>>(
      QKVb, QKVb + E, Sb, nullptr, nullptr, nullptr,
      S, S, E, 3 * E, 3 * E, S, 0.03125f,
      (long long)S * 3 * E, (long long)S * 3 * E, (long long)S * S);

  // ---- softmax
  softmax_rows<<<BS, 256, 0, stream>>>(Sb, Pb, S);

  // ---- O = P . (V^T)^T per batch
  gemm_bt<bf16_t, 0><<<dim3(E / BN, S / BM, B), 256, 0, stream>>>(
      Pb, VTb, Ob, nullptr, nullptr, nullptr,
      S, E, S, S, S, E, 1.f,
      (long long)S * S, (long long)E * S, (long long)S * E);

  // ---- y = O . Wo^T + bo
  gemm_bt<float, 1><<<dim3(E / BN, BS / BM, 1), 256, 0, stream>>>(
      Ob, Wob, out, bo, nullptr, nullptr,
      BS, E, E, E, E, E, 1.f, 0, 0, 0);
}

// Round 6
// 285.521 us; speedup vs baseline: 1.0170x; 1.0170x over previous
//
#include <hip/hip_runtime.h>
#include <hip/hip_bf16.h>

// ---------------------------------------------------------------------------
// SelfAttentionHybrid: single-head attention, B=4 S=2048 E=1024, fp32 in/out.
// R12: revert R11's extra barriers/distance-2 staging (regression: the
// "fixed" vmcnt(0) was never stalling -- loads were L2-warm and 1600 cy old;
// the 2 extra lockstep barriers cost ~600 cy/tile). Back to R10's schedule
// (1 barrier + exact vmcnt(0) per tile, counted-lgkm ladder), with the MFMA
// shape switched 16x16x32 -> 32x32x16: measured ceilings 2495 vs 2176 TF
// (8.07 vs 4.85 cy) => MFMA pipe 2483 -> 2066 cy/tile and half the MFMA
// issue slots. Fragment k-permutation (kc = s + 4*(lane>>5), chunk-XOR slot)
// and C/D map are lifted from the verified 128^2 kernel.
//
// Per-tile schedule (cb = kt&1; bc = B-tj0(kt) regs read at prev ph3):
//  ph0: issue 8 A-M0 reads [(ti,s) order]; stage B(kt+1)->cb^1;
//       LGKM{6,4,2,0} x PAIR(M0,s,bc)                       [no barrier]
//  ph1: issue 4 B-tj1 reads -> bq; stage A(kt+1)->cb^1;
//       LGKM{3,2,1,0} x PAIR(M0,s,bq)                       [no barrier]
//  ph2: issue 8 A-M1 reads; LGKM{6,4,2,0} x PAIR(M1,s,bq);
//       vmcnt(0) [exact: retires the 8 staging loads, ~2 phases old,
//       L2-warm => no stall]; BARRIER  -> buffer cb^1 visible
//  ph3: issue 4 B-tj0(kt+1) reads from cb^1 -> bq (overwrites dead bq;
//       drains under next ph0's LGKM(6)); PAIR(M1,s,bc) reg-only.
// Hazard audit (<=1 tile wave drift, 1 barrier/tile at ph2): after kt's
// barrier, laggards are at kt ph3 (reads Bs[cb^1] tj0 region only, written
// by stageB at kt ph0 BEFORE the barrier -- visible) ; kt+1's ph0 stageB
// writes Bs[cb] whose last readers (kt ph1/ph2 bq reads... tj1 of cb) all
// retired before kt's ph2 barrier. Same discipline as R10 (verified).
// ---------------------------------------------------------------------------

typedef __bf16 bf16_t;
typedef __bf16 bf16x8 __attribute__((ext_vector_type(8)));
typedef __bf16 bf16x4 __attribute__((ext_vector_type(4)));
typedef float  f32x16 __attribute__((ext_vector_type(16)));
typedef float  f32x4  __attribute__((ext_vector_type(4)));

__device__ __forceinline__ void async_copy16(const void* g, void* l) {
  __builtin_amdgcn_global_load_lds(
      (const __attribute__((address_space(1))) void*)g,
      (__attribute__((address_space(3))) void*)l, 16, 0, 0);
}

// raw workgroup barrier: NO vmcnt/lgkmcnt drain (unlike __syncthreads).
__device__ __forceinline__ void wg_barrier() {
  asm volatile("" ::: "memory");
  __builtin_amdgcn_s_barrier();
  asm volatile("" ::: "memory");
}

// counted LDS wait + rule-18 scheduler pin (MFMAs must not hoist above it)
#define LGKM(n)                                                  \
  do {                                                           \
    asm volatile("s_waitcnt lgkmcnt(" #n ")" ::: "memory");      \
    __builtin_amdgcn_sched_barrier(0);                           \
  } while (0)

#define VM(n) asm volatile("s_waitcnt vmcnt(" #n ")" ::: "memory")

// 32-bit LDS byte address (for asm ds_read; invisible to alias analysis)
__device__ __forceinline__ unsigned lds_addr(const void* p) {
  return (unsigned)(unsigned long long)(__attribute__((address_space(3))) const void*)p;
}

// inline-asm LDS read: compiler cannot see this as an LDS access, so it does
// NOT insert vmcnt(0) ordering vs in-flight global_load_lds prefetches.
// Ordering enforced manually via LGKM() + the per-tile vmcnt/barrier.
__device__ __forceinline__ bf16x8 ds_read128(const bf16_t* p) {
  bf16x8 r;
  asm volatile("ds_read_b128 %0, %1" : "=v"(r) : "v"(lds_addr(p)));
  return r;
}

__device__ __forceinline__ f32x16 mfma32(bf16x8 a, bf16x8 b, f32x16 c) {
  return __builtin_amdgcn_mfma_f32_32x32x16_bf16(a, b, c, 0, 0, 0);
}

__device__ __forceinline__ void store_out(float* p, float v)  { *p = v; }
__device__ __forceinline__ void store_out(bf16_t* p, float v) { *p = (bf16_t)v; }

#define BM 128
#define BN 128
#define BKT 64

// 2 MFMA (32x32x16): rows block r0,r0+1 x col block co, k-chunk step s
#define PAIR(r0, s, bb, co)                                        \
  acc[(r0) + 0][co] = mfma32(af[0][s], bb[s], acc[(r0) + 0][co]);  \
  acc[(r0) + 1][co] = mfma32(af[1][s], bb[s], acc[(r0) + 1][co]);

// ---------------------------------------------------------------------------
// gemm256_bt: C[M,N] = A[M,K](lda) x B[N,K](ldb)^T * scale + bias.
// 512 thr = 8 waves (2Mx4N); wave tile 128x64 = 4x2 frags of 32x32x16 MFMA.
// Frag maps (from verified 128^2 kernel): A/B row = blk*32 + (lane&31),
// k-chunk kc = s + 4*(lane>>5) (global k = kc*8+j; A,B use the same
// permutation => contraction order re-permuted, sum exact).
// C/D: col = lane&31, row = (r&3) + 8*(r>>2) + 4*(lane>>5).
// LDS [2 buf][256 rows][64 bf16] per matrix; slot (r,cc) holds global chunk
// cc^(r&7); reads use slot kc^(r&7) (involution).
// Requires M%256==0, N%256==0, K%128==0 (NT even, NT>=4), gridDim.y%8==0.
// ---------------------------------------------------------------------------
template <typename OutT, int NBIAS>
__global__ __launch_bounds__(512, 2) void gemm256_bt(
    const bf16_t* __restrict__ A, const bf16_t* __restrict__ B,
    OutT* __restrict__ C,
    const float* __restrict__ b0, const float* __restrict__ b1,
    const float* __restrict__ b2,
    int M, int N, int K, int lda, int ldb, int ldc, float scale,
    long long strideA, long long strideB, long long strideC) {
  const int z = blockIdx.z;
  A += (long long)z * strideA;
  B += (long long)z * strideB;
  C += (long long)z * strideC;

  // L2 supertile remap: 8 y-tiles per supertile, y-fastest inside.
  int bx = blockIdx.x, by = blockIdx.y;
  {
    const int GX  = gridDim.x;
    const int id  = by * GX + bx;
    const int per = GX * 8;
    const int grp = id / per;
    const int rem = id - grp * per;
    by = grp * 8 + (rem & 7);
    bx = rem >> 3;
  }

  __shared__ __align__(16) bf16_t As[2 * 256 * 64];  // 64 KB
  __shared__ __align__(16) bf16_t Bs[2 * 256 * 64];  // 64 KB

  const int t    = threadIdx.x;
  const int lane = t & 63;
  const int w    = t >> 6;
  const int wm   = w & 1;    // M-half of output tile
  const int wn   = w >> 1;   // N-quarter of output tile
  const int l31  = lane & 31;
  const int h    = lane >> 5;
  const int l7   = lane & 7;
  const int tileM = by * 256;
  const int tileN = bx * 256;

  // staging constants: thread covers chunks t and t+512 of each half-tile
  const int row0 = t >> 3;                    // 0..63
  const int gcc  = (t & 7) ^ (row0 & 7);      // swizzled source chunk
  const int dstb = (t & ~63) * 8;             // wave-uniform LDS base (elems)

  // read constants: swizzled chunk offsets (elems) for k-steps s=0..3
  const int sw0 = ((0 + 4 * h) ^ l7) * 8;
  const int sw1 = ((1 + 4 * h) ^ l7) * 8;
  const int sw2 = ((2 + 4 * h) ^ l7) * 8;
  const int sw3 = ((3 + 4 * h) ^ l7) * 8;
  const int aBase = (wm * 128 + l31) * 64;    // M0 rows; M1 adds 4096
  const int bBase = (wn * 64 + l31) * 64;     // tj0 rows; tj1 adds 2048

  const int NT = K >> 6;

  f32x16 acc[4][2] = {};

  auto stageA = [&](int kt, int hh) {
    const int cb = (kt & 1) * 16384;
    const bf16_t* src =
        A + (long long)(tileM + hh * 128 + row0) * lda + kt * 64 + gcc * 8;
    bf16_t* dst = &As[cb + hh * 8192 + dstb];
    async_copy16(src, dst);
    async_copy16(src + (long long)64 * lda, dst + 4096);
  };
  auto stageB = [&](int kt, int hh) {
    const int cb = (kt & 1) * 16384;
    const bf16_t* src =
        B + (long long)(tileN + hh * 128 + row0) * ldb + kt * 64 + gcc * 8;
    bf16_t* dst = &Bs[cb + hh * 8192 + dstb];
    async_copy16(src, dst);
    async_copy16(src + (long long)64 * ldb, dst + 4096);
  };

  // prologue: stage tile 0 only; retire; pre-read B-tj0(0) (4 reads stay
  // outstanding into tile 0 ph0 -- steady-state invariant).
  stageA(0, 0); stageA(0, 1); stageB(0, 0); stageB(0, 1);
  VM(0);
  wg_barrier();

  bf16x8 af[2][4], P[4], Q[4];
  P[0] = ds_read128(&Bs[bBase + sw0]);
  P[1] = ds_read128(&Bs[bBase + sw1]);
  P[2] = ds_read128(&Bs[bBase + sw2]);
  P[3] = ds_read128(&Bs[bBase + sw3]);

  // bc = B-tj0(kt) (read at prev ph3); bq = scratch: B-tj1(kt), then
  // B-tj0(kt+1).
  auto tile_step = [&](int kt, bf16x8 (&bc)[4], bf16x8 (&bq)[4]) {
    const int cb = (kt & 1) * 16384;
    const int kn = kt + 1;
    const bf16_t* Ab = &As[cb + aBase];
    const bf16_t* Bb = &Bs[cb + bBase];

    // ---- ph0: issue 8 A-M0 reads in ladder order; stage B(kt+1);
    //           MFMA M0 x N0 (bc) on counted lgkm.
    af[0][0] = ds_read128(Ab + sw0);
    af[1][0] = ds_read128(Ab + 2048 + sw0);
    af[0][1] = ds_read128(Ab + sw1);
    af[1][1] = ds_read128(Ab + 2048 + sw1);
    af[0][2] = ds_read128(Ab + sw2);
    af[1][2] = ds_read128(Ab + 2048 + sw2);
    af[0][3] = ds_read128(Ab + sw3);
    af[1][3] = ds_read128(Ab + 2048 + sw3);
    if (kn < NT) { stageB(kn, 0); stageB(kn, 1); }
    __builtin_amdgcn_s_setprio(1);
    LGKM(6);  // retires bc x4 + (ti0,s0),(ti1,s0)
    PAIR(0, 0, bc, 0)
    LGKM(4);
    PAIR(0, 1, bc, 0)
    LGKM(2);
    PAIR(0, 2, bc, 0)
    LGKM(0);
    PAIR(0, 3, bc, 0)
    __builtin_amdgcn_s_setprio(0);

    // ---- ph1: issue 4 B-tj1 reads -> bq; stage A(kt+1); MFMA M0 x N1.
    bq[0] = ds_read128(Bb + 2048 + sw0);
    bq[1] = ds_read128(Bb + 2048 + sw1);
    bq[2] = ds_read128(Bb + 2048 + sw2);
    bq[3] = ds_read128(Bb + 2048 + sw3);
    if (kn < NT) { stageA(kn, 0); stageA(kn, 1); }
    __builtin_amdgcn_s_setprio(1);
    LGKM(3);
    PAIR(0, 0, bq, 1)
    LGKM(2);
    PAIR(0, 1, bq, 1)
    LGKM(1);
    PAIR(0, 2, bq, 1)
    LGKM(0);
    PAIR(0, 3, bq, 1)
    __builtin_amdgcn_s_setprio(0);

    // ---- ph2: issue 8 A-M1 reads; MFMA M1 x N1 (bq); exact vmcnt(0)
    //           [staging ~2 phases old, L2-warm]; barrier.
    af[0][0] = ds_read128(Ab + 4096 + sw0);
    af[1][0] = ds_read128(Ab + 6144 + sw0);
    af[0][1] = ds_read128(Ab + 4096 + sw1);
    af[1][1] = ds_read128(Ab + 6144 + sw1);
    af[0][2] = ds_read128(Ab + 4096 + sw2);
    af[1][2] = ds_read128(Ab + 6144 + sw2);
    af[0][3] = ds_read128(Ab + 4096 + sw3);
    af[1][3] = ds_read128(Ab + 6144 + sw3);
    __builtin_amdgcn_s_setprio(1);
    LGKM(6);
    PAIR(2, 0, bq, 1)
    LGKM(4);
    PAIR(2, 1, bq, 1)
    LGKM(2);
    PAIR(2, 2, bq, 1)
    LGKM(0);
    PAIR(2, 3, bq, 1)
    __builtin_amdgcn_s_setprio(0);
    VM(0);
    wg_barrier();  // buffer (kt+1)&1 now visible to all waves

    // ---- ph3: read B-tj0(kt+1) from cb^1 -> bq (overwrites dead bq;
    //           drains under next ph0's LGKM(6)); MFMA M1 x N0 reg-only.
    if (kn < NT) {
      const bf16_t* Bn = &Bs[(kn & 1) * 16384 + bBase];
      bq[0] = ds_read128(Bn + sw0);
      bq[1] = ds_read128(Bn + sw1);
      bq[2] = ds_read128(Bn + sw2);
      bq[3] = ds_read128(Bn + sw3);
    }
    __builtin_amdgcn_s_setprio(1);
    PAIR(2, 0, bc, 0)
    PAIR(2, 1, bc, 0)
    PAIR(2, 2, bc, 0)
    PAIR(2, 3, bc, 0)
    __builtin_amdgcn_s_setprio(0);
  };

  for (int kt = 0; kt < NT; kt += 2) {
    tile_step(kt,     P, Q);   // bc = P holds Btj0(kt);   Q gets tj1, tj0(kt+1)
    tile_step(kt + 1, Q, P);   // bc = Q holds Btj0(kt+1); P gets tj1, tj0(kt+2)
  }

  // epilogue: 32x32 C map: col = lane&31, row = (r&3) + 8*(r>>2) + 4*h.
  float bvv[2];
#pragma unroll
  for (int tj = 0; tj < 2; ++tj) {
    const int col = tileN + wn * 64 + tj * 32 + l31;
    float bv = 0.f;
    if (NBIAS == 1) bv = b0[col];
    if (NBIAS == 3) {
      const float* bp = col < 1024 ? b0 : (col < 2048 ? b1 : b2);
      bv = bp[col & 1023];
    }
    bvv[tj] = bv;
  }
#pragma unroll
  for (int ti = 0; ti < 4; ++ti) {
#pragma unroll
    for (int r = 0; r < 16; ++r) {
      const long long row =
          tileM + wm * 128 + ti * 32 + 4 * h + (r & 3) + 8 * (r >> 2);
      OutT* Crow = C + row * ldc + tileN + wn * 64 + l31;
#pragma unroll
      for (int tj = 0; tj < 2; ++tj)
        store_out(Crow + tj * 32, acc[ti][tj][r] * scale + bvv[tj]);
    }
  }
}

// ---------------------------------------------------------------------------
// 128^2 kernel (R6) — kept for PV and output GEMMs (their 256^2 grids would
// be 128 blocks = half the CUs).
// ---------------------------------------------------------------------------
template <typename OutT, int NBIAS>
__global__ __launch_bounds__(256) void gemm_bt(
    const bf16_t* __restrict__ A, const bf16_t* __restrict__ B,
    OutT* __restrict__ C,
    const float* __restrict__ b0, const float* __restrict__ b1,
    const float* __restrict__ b2,
    int M, int N, int K, int lda, int ldb, int ldc, float scale,
    long long strideA, long long strideB, long long strideC) {
  const int z = blockIdx.z;
  A += (long long)z * strideA;
  B += (long long)z * strideB;
  C += (long long)z * strideC;

  int bx = blockIdx.x, by = blockIdx.y;
  {
    const int GX  = gridDim.x;
    const int id  = by * GX + bx;
    const int per = GX * 8;
    const int grp = id / per;
    const int rem = id - grp * per;
    by = grp * 8 + (rem & 7);
    bx = rem >> 3;
  }

  __shared__ __align__(16) bf16_t As[BM * BKT];  // 16 KB
  __shared__ __align__(16) bf16_t Bs[BN * BKT];  // 16 KB

  const int t    = threadIdx.x;
  const int lane = t & 63;
  const int w    = t >> 6;
  const int wm   = w & 1;
  const int wn   = w >> 1;
  const int tileM = by * BM;
  const int tileN = bx * BN;

  f32x16 acc[2][2] = {};

  for (int k0 = 0; k0 < K; k0 += BKT) {
#pragma unroll
    for (int i = 0; i < 4; ++i) {
      const int c   = t + 256 * i;
      const int row = c >> 3;
      const int cc  = c & 7;
      const int gcc = cc ^ (row & 7);
      const int ldsbase = ((t & ~63) + 256 * i) * 8;
      async_copy16(A + (long long)(tileM + row) * lda + k0 + gcc * 8, &As[ldsbase]);
      async_copy16(B + (long long)(tileN + row) * ldb + k0 + gcc * 8, &Bs[ldsbase]);
    }
    __syncthreads();

#pragma unroll
    for (int s = 0; s < 4; ++s) {
      const int kc = s + 4 * (lane >> 5);
      bf16x8 af[2], bfr[2];
#pragma unroll
      for (int ti = 0; ti < 2; ++ti) {
        const int row = wm * 64 + ti * 32 + (lane & 31);
        af[ti] = *(const bf16x8*)&As[row * BKT + ((kc ^ (row & 7)) * 8)];
      }
#pragma unroll
      for (int tj = 0; tj < 2; ++tj) {
        const int row = wn * 64 + tj * 32 + (lane & 31);
        bfr[tj] = *(const bf16x8*)&Bs[row * BKT + ((kc ^ (row & 7)) * 8)];
      }
#pragma unroll
      for (int ti = 0; ti < 2; ++ti)
#pragma unroll
        for (int tj = 0; tj < 2; ++tj)
          acc[ti][tj] = __builtin_amdgcn_mfma_f32_32x32x16_bf16(
              af[ti], bfr[tj], acc[ti][tj], 0, 0, 0);
    }
    __syncthreads();
  }

#pragma unroll
  for (int tj = 0; tj < 2; ++tj) {
    const int col = tileN + wn * 64 + tj * 32 + (lane & 31);
    float bv = 0.f;
    if (NBIAS == 1) bv = b0[col];
    if (NBIAS == 3) {
      const float* bp = col < 1024 ? b0 : (col < 2048 ? b1 : b2);
      bv = bp[col & 1023];
    }
#pragma unroll
    for (int ti = 0; ti < 2; ++ti) {
      const int rowb = tileM + wm * 64 + ti * 32 + 4 * (lane >> 5);
#pragma unroll
      for (int r = 0; r < 16; ++r) {
        const int row = rowb + (r & 3) + 8 * (r >> 2);
        store_out(&C[(long long)row * ldc + col], acc[ti][tj][r] * scale + bv);
      }
    }
  }
}

// ---------------------------------------------------------------------------
// fused cast: all 4 weights + x in one dispatch (flat grid, region decode).
// ---------------------------------------------------------------------------
__global__ __launch_bounds__(256) void cast_all(
    const float4* __restrict__ w0, const float4* __restrict__ w1,
    const float4* __restrict__ w2, const float4* __restrict__ w3,
    const float4* __restrict__ x,
    bf16x4* __restrict__ wdst, bf16x4* __restrict__ xdst) {
  const int N4W = 1 << 18;  // 1024*1024/4
  const int id = blockIdx.x * 256 + threadIdx.x;
  const float4* src;
  bf16x4* dst;
  if (id < 4 * N4W) {
    const int z = id >> 18;
    src = (z == 0 ? w0 : z == 1 ? w1 : z == 2 ? w2 : w3) + (id & (N4W - 1));
    dst = wdst + id;
  } else {
    const int i = id - 4 * N4W;
    src = x + i;
    dst = xdst + i;
  }
  const float4 v = *src;
  bf16x4 o;
  o[0] = (bf16_t)v.x; o[1] = (bf16_t)v.y; o[2] = (bf16_t)v.z; o[3] = (bf16_t)v.w;
  *dst = o;
}

// ---------------------------------------------------------------------------
// bf16 transpose [R,C](ldin) -> [C,R], batched via blockIdx.z
// ---------------------------------------------------------------------------
__global__ __launch_bounds__(256) void transpose_bf16(
    const bf16_t* __restrict__ in, bf16_t* __restrict__ out, int R, int C,
    int ldin, long long sIn, long long sOut) {
  in  += (long long)blockIdx.z * sIn;
  out += (long long)blockIdx.z * sOut;
  __shared__ bf16_t tile[32][33];
  const int tx = threadIdx.x, ty = threadIdx.y;
  const int x = blockIdx.x * 32 + tx;
  const int y0 = blockIdx.y * 32;
#pragma unroll
  for (int j = 0; j < 32; j += 8)
    tile[ty + j][tx] = in[(long long)(y0 + ty + j) * ldin + x];
  __syncthreads();
  const int x2 = y0 + tx;
  const int y2 = blockIdx.x * 32;
#pragma unroll
  for (int j = 0; j < 32; j += 8)
    out[(long long)(y2 + ty + j) * R + x2] = tile[tx][ty + j];
}

// ---------------------------------------------------------------------------
// row softmax: 2048-wide rows, 256 threads x 8 elems
// ---------------------------------------------------------------------------
__global__ __launch_bounds__(256) void softmax_rows(
    const bf16_t* __restrict__ S, bf16_t* __restrict__ P, int cols) {
  const long long row = blockIdx.x;
  const bf16x8* inp = (const bf16x8*)(S + row * cols);
  bf16x8* outp      = (bf16x8*)(P + row * cols);
  const int t = threadIdx.x;
  const int w = t >> 6, lane = t & 63;

  const bf16x8 v = inp[t];
  float f[8];
#pragma unroll
  for (int j = 0; j < 8; ++j) f[j] = (float)v[j];

  float m = f[0];
#pragma unroll
  for (int j = 1; j < 8; ++j) m = fmaxf(m, f[j]);
#pragma unroll
  for (int off = 32; off > 0; off >>= 1) m = fmaxf(m, __shfl_xor(m, off));

  __shared__ float red[8];
  if (lane == 0) red[w] = m;
  __syncthreads();
  m = fmaxf(fmaxf(red[0], red[1]), fmaxf(red[2], red[3]));

  float e[8], sum = 0.f;
#pragma unroll
  for (int j = 0; j < 8; ++j) { e[j] = __expf(f[j] - m); sum += e[j]; }
#pragma unroll
  for (int off = 32; off > 0; off >>= 1) sum += __shfl_xor(sum, off);
  if (lane == 0) red[4 + w] = sum;
  __syncthreads();
  sum = red[4] + red[5] + red[6] + red[7];

  const float inv = 1.f / sum;
  bf16x8 o;
#pragma unroll
  for (int j = 0; j < 8; ++j) o[j] = (bf16_t)(e[j] * inv);
  outp[t] = o;
}

// ---------------------------------------------------------------------------
extern "C" void kernel_launch(void* const* d_in, const int* in_sizes, int n_in,
                              void* d_out, int out_size, void* d_ws, size_t ws_size,
                              hipStream_t stream) {
  const int E = 1024, S = 2048, B = 4;
  const int BS = B * S;  // 8192

  const float* x  = (const float*)d_in[0];
  const float* Wq = (const float*)d_in[1];
  const float* bq = (const float*)d_in[2];
  const float* Wk = (const float*)d_in[3];
  const float* bk = (const float*)d_in[4];
  const float* Wv = (const float*)d_in[5];
  const float* bv = (const float*)d_in[6];
  const float* Wo = (const float*)d_in[7];
  const float* bo = (const float*)d_in[8];
  float* out = (float*)d_out;

  char* w = (char*)d_ws;
  const size_t MB = 1ull << 20;
  bf16_t* Wqkvb = (bf16_t*)(w + 0 * MB);          // 6 MB  [3072,1024]
  bf16_t* Wob   = Wqkvb + 3 * E * E;              // 2 MB
  bf16_t* xb    = (bf16_t*)(w + 8 * MB);          // 16 MB [8192,1024]
  bf16_t* QKVb  = (bf16_t*)(w + 24 * MB);         // 48 MB [8192,3072]
  bf16_t* VTb   = (bf16_t*)(w + 72 * MB);         // 16 MB [B][1024,2048]
  bf16_t* Sb    = (bf16_t*)(w + 88 * MB);         // 32 MB scores
  bf16_t* Pb    = (bf16_t*)(w + 8 * MB);          // 32 MB (xb + QKV[0:16MB] dead)
  bf16_t* Ob    = (bf16_t*)(w + 40 * MB);         // 16 MB (QKV[16:32MB] dead)

  // ---- all casts in one dispatch
  {
    const int totalBlocks = ((4 << 18) + (1 << 21)) / 256;  // 12288
    cast_all<<<totalBlocks, 256, 0, stream>>>(
        (const float4*)Wq, (const float4*)Wk, (const float4*)Wv,
        (const float4*)Wo, (const float4*)x, (bf16x4*)Wqkvb, (bf16x4*)xb);
  }

  // ---- fused QKV projection: [8192,3072] = xb . Wqkv^T + (bq|bk|bv)
  gemm256_bt<bf16_t, 3><<<dim3(3 * E / 256, BS / 256, 1), 512, 0, stream>>>(
      xb, Wqkvb, QKVb, bq, bk, bv,
      BS, 3 * E, E, E, E, 3 * E, 1.f, 0, 0, 0);

  // ---- V^T per batch: [2048,1024](ld 3072) -> [1024,2048]
  transpose_bf16<<<dim3(E / 32, S / 32, B), dim3(32, 8), 0, stream>>>(
      QKVb + 2 * E, VTb, S, E, 3 * E, (long long)S * 3 * E, (long long)E * S);

  // ---- scores = Q . K^T * E^-0.5 per batch
  gemm256_bt<bf16_t, 0><<<dim3(S / 256, S / 256, B), 512, 0, stream>>>(
      QKVb, QKVb + E, Sb, nullptr, nullptr, nullptr,
      S, S, E, 3 * E, 3 * E, S, 0.03125f,
      (long long)S * 3 * E, (long long)S * 3 * E, (long long)S * S);

  // ---- softmax
  softmax_rows<<<BS, 256, 0, stream>>>(Sb, Pb, S);

  // ---- O = P . (V^T)^T per batch
  gemm_bt<bf16_t, 0><<<dim3(E / BN, S / BM, B), 256, 0, stream>>>(
      Pb, VTb, Ob, nullptr, nullptr, nullptr,
      S, E, S, S, S, E, 1.f,
      (long long)S * S, (long long)E * S, (long long)S * E);

  // ---- y = O . Wo^T + bo
  gemm_bt<float, 1><<<dim3(E / BN, BS / BM, 1), 256, 0, stream>>>(
      Ob, Wob, out, bo, nullptr, nullptr,
      BS, E, E, E, E, E, 1.f, 0, 0, 0);
}